// Round 8
// baseline (162.850 us; speedup 1.0000x reference)
//
#include <hip/hip_runtime.h>
#include <stdint.h>

#define B_   16384
#define D_   512
#define N1_  1024   // 2D
#define K1_  512    // D
#define N2_  512
#define K2_  1024

#define DELTA     4e-3f
#define RCAP      16u          // per-row bucket capacity (Poisson mean 3.3)
#define OCAP      32u          // overflow list capacity

typedef _Float16 f16x8 __attribute__((ext_vector_type(8)));
typedef _Float16 f16x4 __attribute__((ext_vector_type(4)));
typedef float    f32x4 __attribute__((ext_vector_type(4)));

#define MFMA(a, b, c) __builtin_amdgcn_mfma_f32_16x16x32_f16(a, b, c, 0, 0, 0)

// ---------------- prep: frag-major permuted weights + biases + cvec ----------------
// wp: 64 slices x 32 KB. Slice g (ch=g>>5, ph=g&31): ph<16 -> W1 cols ch*512..,
// k=ph*32 (x64 scale); ph>=16 -> W2 all 512 dz-cols, k=ch*512+(ph-16)*32.
// Within a slice: [wave w: 4KB][nt 0..3: 1KB][lane: 16B] = exactly the A-operand
// fragment each lane consumes -> 16B/lane coalesced loads, weights never in LDS.
// (Identical layout to r5-r7: block-size change doesn't alter wave->col mapping.)
__global__ __launch_bounds__(256) void prep_w(
    const float* __restrict__ t,
    const float* __restrict__ W1, const float* __restrict__ b1,
    const float* __restrict__ W2, const float* __restrict__ b2,
    _Float16* __restrict__ wp,
    float* __restrict__ bias1, float* __restrict__ bias2,
    float* __restrict__ cvec) {
  int blk = blockIdx.x, tid = threadIdx.x;
  if (blk < 512) {                                  // 131072 granules of 16 B
    int idx = blk * 256 + tid;
    int g = idx >> 11, rem = idx & 2047;
    int w = rem >> 8, nt = (rem >> 6) & 3, lane = rem & 63;
    int m16 = lane & 15, q = lane >> 4;
    int ch = g >> 5, ph = g & 31;
    const float* src;
    float scale;
    if (ph < 16) {                                  // W1 frag: m=h-col, k
      int col = ch * 512 + w * 64 + nt * 16 + m16;
      int k = ph * 32 + q * 8;
      src = W1 + (size_t)col * 513 + k;
      scale = 64.f;
    } else {                                        // W2 frag: m=dz-col, k=h-col
      int col = w * 64 + nt * 16 + m16;
      int k = ch * 512 + (ph - 16) * 32 + q * 8;
      src = W2 + (size_t)col * 1025 + k;
      scale = 1.f;
    }
    f16x8 hv;
    #pragma unroll
    for (int e = 0; e < 8; ++e) hv[e] = (_Float16)(src[e] * scale);
    *(f16x8*)(wp + (size_t)idx * 8) = hv;
  } else if (blk < 516) {                           // biases
    int j = (blk - 512) * 256 + tid;                // [0, 1024)
    float t0 = t[0];
    bias1[j] = b1[j] + t0 * W1[(size_t)j * 513 + 512];
    if (j < 512) bias2[j] = b2[j] + t0 * W2[(size_t)j * 1025 + 1024];
  } else {                                          // c[j] = sum_k W2[k,j]*W1[j,k]
    int wave = tid >> 6, lane = tid & 63;
    int j = (blk - 516) * 4 + wave;                 // [0, 1024)
    float s = 0.f;
    #pragma unroll
    for (int kk = 0; kk < 8; ++kk) {
      int k = lane + kk * 64;
      s += W2[(size_t)k * 1025 + j] * W1[(size_t)j * 513 + k];
    }
    #pragma unroll
    for (int off = 32; off > 0; off >>= 1) s += __shfl_xor(s, off);
    if (lane == 0) cvec[j] = s;
  }
}

// ---------------- fused: 32-row blocks, 2 blocks/CU (4 waves/SIMD) ----------------
// Block = 32 z-rows, 512 threads (8 waves), grid 512 (2 blocks/CU).
// Wave w owns cols [w*64,+64) of each 512-col chunk (GEMM1) and of dz (GEMM2);
// per-wave tile 32x64 -> acc = 64 AGPRs, single-buffered weight stream keeps
// combined regs <= 128 (enforced: __launch_bounds__(512,4)) so BOTH blocks stay
// resident. 4 waves/SIMD TLP hides L2/LDS latency that r5-r7's 2 waves couldn't.
// LDS ~77 KB: Az 32KB + Hb 32KB + biases/cvec/buckets. Barriers are per-block:
// the co-resident block keeps the SIMDs fed through Hb handoffs.
// Borderline ReLU entries bucketed BY ROW; tail re-verifies in f32 (wave owns 4 rows).

__global__ __launch_bounds__(512, 4) void fused_kernel(
    const float* __restrict__ z, const _Float16* __restrict__ wp,
    const float* __restrict__ W1f,
    const float* __restrict__ bias1, const float* __restrict__ bias2,
    const float* __restrict__ cvec,
    float* __restrict__ out, float* __restrict__ dlogp) {
  __shared__ __align__(16) _Float16 Az[32 * 512];   // 32 KB swizzled z (f16 x16)
  __shared__ __align__(16) _Float16 Hb[32 * 512];   // 32 KB swizzled h chunk
  __shared__ __align__(16) float bias1L[1024];      // 4 KB
  __shared__ __align__(16) float cvecL[1024];       // 4 KB
  __shared__ uint32_t rbuck[32][RCAP];              // 2 KB row-bucketed borderline
  __shared__ uint32_t rbcnt[32];                    // 128 B
  __shared__ uint32_t ovf[OCAP];                    // 128 B
  __shared__ float redbuf[8][32];                   // 1 KB
  __shared__ float fixv[32];                        // wave-owned corrections
  __shared__ float fixo[32];                        // overflow corrections
  __shared__ uint32_t ovfcnt;                       // ~77.3 KB total

  const int tid  = threadIdx.x;
  const int lane = tid & 63, w = tid >> 6;          // wave 0..7
  const int q    = lane >> 4, m16 = lane & 15;
  const int sw   = m16 & 7;
  const int bm   = blockIdx.x;                      // 512 blocks x 32 rows

  if (tid < 32) { rbcnt[tid] = 0; fixo[tid] = 0.f; }
  if (tid == 0) ovfcnt = 0;

  // ---- stage z (f32 -> f16 x16) into swizzled Az: 32x512 ----
  {
    const float* zp = z + (size_t)bm * 32 * 512;
    #pragma unroll
    for (int i = 0; i < 8; ++i) {
      int slot = i * 512 + tid;                     // [0,4096) f32x4 slots
      int row = slot >> 7, u8 = slot & 127;
      f32x4 v = *(const f32x4*)(zp + (size_t)row * 512 + u8 * 4);
      f16x4 hv;
      #pragma unroll
      for (int r = 0; r < 4; ++r) hv[r] = (_Float16)(v[r] * 16.f);
      int gz = (u8 >> 1) ^ (row & 7);
      *(f16x4*)((char*)Az + row * 1024 + gz * 16 + (u8 & 1) * 8) = hv;
    }
  }
  for (int i = tid; i < 1024; i += 512) {
    bias1L[i] = bias1[i];
    cvecL[i]  = cvec[i];
  }
  __syncthreads();

  f32x4 acc1[2][4] = {};                            // GEMM1: [mt(row16)][nt(col16)]
  f32x4 acc2[2][4] = {};                            // GEMM2 accumulates across chunks
  float tr[2] = {0.f, 0.f};

  const char* azb   = (const char*)Az + m16 * 1024;
  const char* hbb   = (const char*)Hb + m16 * 1024;
  const char* wbase = (const char*)wp + w * 4096 + lane * 16;

  for (int ch = 0; ch < 2; ++ch) {
    // ---- GEMM1: 16 k32-slices, h_pre chunk (cols ch*512..+512) ----
    #pragma unroll 4
    for (int s = 0; s < 16; ++s) {
      const char* wsl = wbase + (size_t)(ch * 32 + s) * 32768;
      f16x8 cw0 = *(const f16x8*)(wsl);
      f16x8 cw1 = *(const f16x8*)(wsl + 1024);
      f16x8 cw2 = *(const f16x8*)(wsl + 2048);
      f16x8 cw3 = *(const f16x8*)(wsl + 3072);
      const int zg = ((s * 4 + q) ^ sw) << 4;
      f16x8 zf0 = *(const f16x8*)(azb + zg);
      f16x8 zf1 = *(const f16x8*)(azb + 16384 + zg);
      __builtin_amdgcn_s_setprio(1);
      acc1[0][0] = MFMA(cw0, zf0, acc1[0][0]);
      acc1[0][1] = MFMA(cw1, zf0, acc1[0][1]);
      acc1[0][2] = MFMA(cw2, zf0, acc1[0][2]);
      acc1[0][3] = MFMA(cw3, zf0, acc1[0][3]);
      acc1[1][0] = MFMA(cw0, zf1, acc1[1][0]);
      acc1[1][1] = MFMA(cw1, zf1, acc1[1][1]);
      acc1[1][2] = MFMA(cw2, zf1, acc1[1][2]);
      acc1[1][3] = MFMA(cw3, zf1, acc1[1][3]);
      __builtin_amdgcn_s_setprio(0);
    }

    __syncthreads();   // A: all waves finished reading Hb in previous GEMM2

    // ---- chunk epilogue: bias+relu, trace, row-bucketed borderline, h -> Hb ----
    #pragma unroll
    for (int nt = 0; nt < 4; ++nt) {
      int colc = w * 64 + nt * 16 + q * 4;          // chunk-local col
      int col = ch * 512 + colc;
      f32x4 b4 = *(const f32x4*)&bias1L[col];
      f32x4 c4 = *(const f32x4*)&cvecL[col];
      #pragma unroll
      for (int mt = 0; mt < 2; ++mt) {
        int row = mt * 16 + m16;
        f16x4 hv;
        #pragma unroll
        for (int r = 0; r < 4; ++r) {
          float hp = acc1[mt][nt][r] * (1.f / 1024.f) + b4[r];
          hv[r] = (_Float16)(hp > 0.f ? hp : 0.f);
          if (hp > 0.f) tr[mt] += c4[r];
          if (__builtin_fabsf(hp) < DELTA) {
            uint32_t e = (uint32_t)(col + r) | (hp > 0.f ? 0x80000000u : 0u);
            uint32_t bi = atomicAdd(&rbcnt[row], 1u);   // LDS atomic: cheap
            if (bi < RCAP) rbuck[row][bi] = e;
            else {
              uint32_t oi = atomicAdd(&ovfcnt, 1u);
              if (oi < OCAP) ovf[oi] = ((uint32_t)row << 10) | e;
            }
          }
        }
        int gg = (colc >> 3) ^ (row & 7);
        *(f16x4*)((char*)Hb + row * 1024 + gg * 16 + (q & 1) * 8) = hv;
        acc1[mt][nt] = (f32x4){0.f, 0.f, 0.f, 0.f};
      }
    }

    __syncthreads();   // B: Hb(ch) visible to all waves

    // ---- GEMM2: 16 k32-slices, dz += h_chunk @ W2[:, ch*512..]^T ----
    #pragma unroll 4
    for (int t = 0; t < 16; ++t) {
      const char* wsl = wbase + (size_t)(ch * 32 + 16 + t) * 32768;
      f16x8 cw0 = *(const f16x8*)(wsl);
      f16x8 cw1 = *(const f16x8*)(wsl + 1024);
      f16x8 cw2 = *(const f16x8*)(wsl + 2048);
      f16x8 cw3 = *(const f16x8*)(wsl + 3072);
      const int hg = ((t * 4 + q) ^ sw) << 4;
      f16x8 hf0 = *(const f16x8*)(hbb + hg);
      f16x8 hf1 = *(const f16x8*)(hbb + 16384 + hg);
      __builtin_amdgcn_s_setprio(1);
      acc2[0][0] = MFMA(cw0, hf0, acc2[0][0]);
      acc2[0][1] = MFMA(cw1, hf0, acc2[0][1]);
      acc2[0][2] = MFMA(cw2, hf0, acc2[0][2]);
      acc2[0][3] = MFMA(cw3, hf0, acc2[0][3]);
      acc2[1][0] = MFMA(cw0, hf1, acc2[1][0]);
      acc2[1][1] = MFMA(cw1, hf1, acc2[1][1]);
      acc2[1][2] = MFMA(cw2, hf1, acc2[1][2]);
      acc2[1][3] = MFMA(cw3, hf1, acc2[1][3]);
      __builtin_amdgcn_s_setprio(0);
    }
  }

  // ---- dz store: +bias2, f32x4 (4 consecutive cols per thread) ----
  #pragma unroll
  for (int mt = 0; mt < 2; ++mt) {
    int row = bm * 32 + mt * 16 + m16;
    #pragma unroll
    for (int nt = 0; nt < 4; ++nt) {
      int col = w * 64 + nt * 16 + q * 4;
      f32x4 b2v = *(const f32x4*)(bias2 + col);
      *(f32x4*)(out + (size_t)row * 512 + col) = acc2[mt][nt] + b2v;
    }
  }

  // ---- trace: block-local partials to LDS ----
  #pragma unroll
  for (int mt = 0; mt < 2; ++mt) {
    tr[mt] += __shfl_xor(tr[mt], 16);
    tr[mt] += __shfl_xor(tr[mt], 32);
  }
  if (q == 0) {
    #pragma unroll
    for (int mt = 0; mt < 2; ++mt) redbuf[w][mt * 16 + m16] = tr[mt];
  }
  __syncthreads();   // redbuf + rbuck/rbcnt/ovf final

  // ---- in-block fixup: wave w owns rows [w*4, +4); z row read ONCE per row ----
  #pragma unroll 1
  for (int r4 = 0; r4 < 4; ++r4) {
    int row = w * 4 + r4;
    uint32_t cnt = rbcnt[row];
    if (cnt > RCAP) cnt = RCAP;
    float corr = 0.f;
    if (cnt) {
      const float* zr = z + ((size_t)(bm * 32 + row)) * 512;
      float zv[8];
      #pragma unroll
      for (int it = 0; it < 8; ++it) zv[it] = zr[it * 64 + lane];
      for (uint32_t e = 0; e < cnt; ++e) {
        uint32_t en = rbuck[row][e];
        int col  = (int)(en & 1023u);
        int oldm = (int)(en >> 31);
        const float* wc = W1f + (size_t)col * 513;
        float s = 0.f;
        #pragma unroll
        for (int it = 0; it < 8; ++it) s += zv[it] * wc[it * 64 + lane];
        #pragma unroll
        for (int off = 32; off > 0; off >>= 1) s += __shfl_xor(s, off);
        float hp = s + bias1L[col];
        int newm = hp > 0.f ? 1 : 0;
        if (newm != oldm) corr += oldm ? cvecL[col] : -cvecL[col];
      }
    }
    if (lane == 0) fixv[row] = corr;               // wave-owned: plain store
  }
  // overflow entries (statistically never; correctness safety net)
  {
    uint32_t on = ovfcnt;
    if (on > OCAP) on = OCAP;
    for (uint32_t i = w; i < on; i += 8) {
      uint32_t e = ovf[i];
      int row  = (int)((e >> 10) & 31u);
      int col  = (int)(e & 1023u);
      int oldm = (int)(e >> 31);
      const float* zr = z + ((size_t)(bm * 32 + row)) * 512;
      const float* wc = W1f + (size_t)col * 513;
      float s = 0.f;
      #pragma unroll
      for (int it = 0; it < 8; ++it) {
        int k = it * 64 + lane;
        s += zr[k] * wc[k];
      }
      #pragma unroll
      for (int off = 32; off > 0; off >>= 1) s += __shfl_xor(s, off);
      if (lane == 0) {
        float hp = s + bias1L[col];
        int newm = hp > 0.f ? 1 : 0;
        if (newm != oldm) atomicAdd(&fixo[row], oldm ? cvecL[col] : -cvecL[col]);
      }
    }
  }
  __syncthreads();

  // ---- final dlogp: -(trace) + corrections, deterministic store ----
  if (tid < 32) {
    float s = 0.f;
    #pragma unroll
    for (int ww = 0; ww < 8; ++ww) s += redbuf[ww][tid];
    dlogp[bm * 32 + tid] = -s + fixv[tid] + fixo[tid];
  }
}

// ---------------- launcher ----------------
extern "C" void kernel_launch(void* const* d_in, const int* in_sizes, int n_in,
                              void* d_out, int out_size, void* d_ws, size_t ws_size,
                              hipStream_t stream) {
  const float* t  = (const float*)d_in[0];
  const float* z  = (const float*)d_in[1];
  // d_in[2] = logp_z, unused
  const float* W1 = (const float*)d_in[3];
  const float* b1 = (const float*)d_in[4];
  const float* W2 = (const float*)d_in[5];
  const float* b2 = (const float*)d_in[6];

  float* out   = (float*)d_out;
  float* dlogp = out + (size_t)B_ * D_;

  char* ws = (char*)d_ws;
  _Float16* wp    = (_Float16*)ws; ws += (size_t)64 * 32768;     // 2 MB permuted weights
  float*    bias1 = (float*)ws;    ws += 1024 * 4;
  float*    bias2 = (float*)ws;    ws += 512 * 4;
  float*    cvec  = (float*)ws;    ws += 1024 * 4;

  prep_w<<<772, 256, 0, stream>>>(t, W1, b1, W2, b2, wp, bias1, bias2, cvec);
  fused_kernel<<<512, 512, 0, stream>>>(z, wp, W1, bias1, bias2, cvec, out, dlogp);
}

// Round 9
// 159.551 us; speedup vs baseline: 1.0207x; 1.0207x over previous
//
#include <hip/hip_runtime.h>
#include <stdint.h>

#define B_   16384
#define D_   512
#define N1_  1024   // 2D
#define K1_  512    // D
#define N2_  512
#define K2_  1024

#define DELTA     4e-3f
#define RCAP      16u          // per-row bucket capacity (Poisson mean 3.3)
#define OCAP      32u          // overflow list capacity

typedef _Float16 f16x8 __attribute__((ext_vector_type(8)));
typedef _Float16 f16x4 __attribute__((ext_vector_type(4)));
typedef float    f32x4 __attribute__((ext_vector_type(4)));

#define MFMA(a, b, c) __builtin_amdgcn_mfma_f32_16x16x32_f16(a, b, c, 0, 0, 0)

// ---------------- prep: frag-major permuted weights + biases + cvec ----------------
// wp: 64 slices x 32 KB. Slice g (ch=g>>5, ph=g&31): ph<16 -> W1 cols ch*512..,
// k=ph*32 (x64 scale); ph>=16 -> W2 all 512 dz-cols, k=ch*512+(ph-16)*32.
// Slice bytes: [w8: 4KB][nt4: 1KB][lane: 16B]. A 16-wave consumer maps wave w'
// to (w8 = w'>>1, nt pair = (w'&1)*2+{0,1}) -> layout unchanged from r5-r8.
__global__ __launch_bounds__(256) void prep_w(
    const float* __restrict__ t,
    const float* __restrict__ W1, const float* __restrict__ b1,
    const float* __restrict__ W2, const float* __restrict__ b2,
    _Float16* __restrict__ wp,
    float* __restrict__ bias1, float* __restrict__ bias2,
    float* __restrict__ cvec) {
  int blk = blockIdx.x, tid = threadIdx.x;
  if (blk < 512) {                                  // 131072 granules of 16 B
    int idx = blk * 256 + tid;
    int g = idx >> 11, rem = idx & 2047;
    int w = rem >> 8, nt = (rem >> 6) & 3, lane = rem & 63;
    int m16 = lane & 15, q = lane >> 4;
    int ch = g >> 5, ph = g & 31;
    const float* src;
    float scale;
    if (ph < 16) {                                  // W1 frag: m=h-col, k
      int col = ch * 512 + w * 64 + nt * 16 + m16;
      int k = ph * 32 + q * 8;
      src = W1 + (size_t)col * 513 + k;
      scale = 64.f;
    } else {                                        // W2 frag: m=dz-col, k=h-col
      int col = w * 64 + nt * 16 + m16;
      int k = ch * 512 + (ph - 16) * 32 + q * 8;
      src = W2 + (size_t)col * 1025 + k;
      scale = 1.f;
    }
    f16x8 hv;
    #pragma unroll
    for (int e = 0; e < 8; ++e) hv[e] = (_Float16)(src[e] * scale);
    *(f16x8*)(wp + (size_t)idx * 8) = hv;
  } else if (blk < 516) {                           // biases
    int j = (blk - 512) * 256 + tid;                // [0, 1024)
    float t0 = t[0];
    bias1[j] = b1[j] + t0 * W1[(size_t)j * 513 + 512];
    if (j < 512) bias2[j] = b2[j] + t0 * W2[(size_t)j * 1025 + 1024];
  } else {                                          // c[j] = sum_k W2[k,j]*W1[j,k]
    int wave = tid >> 6, lane = tid & 63;
    int j = (blk - 516) * 4 + wave;                 // [0, 1024)
    float s = 0.f;
    #pragma unroll
    for (int kk = 0; kk < 8; ++kk) {
      int k = lane + kk * 64;
      s += W2[(size_t)k * 1025 + j] * W1[(size_t)j * 513 + k];
    }
    #pragma unroll
    for (int off = 32; off > 0; off >>= 1) s += __shfl_xor(s, off);
    if (lane == 0) cvec[j] = s;
  }
}

// ---------------- fused: 64-row block, 16 waves (4/SIMD), dbuf weight stream ----------------
// Block = 64 z-rows, 1024 threads (16 waves), grid 256 (1 block/CU).
// Same per-CU totals as r7 (2 MB weight stream/CU, same MFMA count, ~148KB LDS)
// but 4 waves/SIMD of TLP instead of 2: wave tile 64x32 (acc=64 AGPR), leaving
// register room (<=128/wave unified) for the r7 double-buffered weight stream.
// Tail: 16 waves x 4 rows, W1-column loads 2-deep software-pipelined.

__global__ __launch_bounds__(1024, 4) void fused_kernel(
    const float* __restrict__ z, const _Float16* __restrict__ wp,
    const float* __restrict__ W1f,
    const float* __restrict__ bias1, const float* __restrict__ bias2,
    const float* __restrict__ cvec,
    float* __restrict__ out, float* __restrict__ dlogp) {
  __shared__ __align__(16) _Float16 Az[64 * 512];   // 64 KB swizzled z (f16 x16)
  __shared__ __align__(16) _Float16 Hb[64 * 512];   // 64 KB swizzled h chunk
  __shared__ __align__(16) float bias1L[1024];      // 4 KB
  __shared__ __align__(16) float cvecL[1024];       // 4 KB
  __shared__ uint32_t rbuck[64][RCAP];              // 4 KB row-bucketed borderline
  __shared__ uint32_t rbcnt[64];                    // 256 B
  __shared__ uint32_t ovf[OCAP];                    // 128 B
  __shared__ float redbuf[16][64];                  // 4 KB
  __shared__ float fixv[64];                        // wave-owned corrections
  __shared__ float fixo[64];                        // overflow corrections
  __shared__ uint32_t ovfcnt;                       // ~148.6 KB total

  const int tid  = threadIdx.x;
  const int lane = tid & 63, w = tid >> 6;          // wave 0..15
  const int q    = lane >> 4, m16 = lane & 15;
  const int sw   = m16 & 7;
  const int bm   = blockIdx.x;                      // 256 blocks x 64 rows

  if (tid < 64) { rbcnt[tid] = 0; fixo[tid] = 0.f; }
  if (tid == 0) ovfcnt = 0;

  // ---- stage z (f32 -> f16 x16) into swizzled Az: 64x512 ----
  {
    const float* zp = z + (size_t)bm * 64 * 512;
    #pragma unroll
    for (int i = 0; i < 8; ++i) {
      int slot = i * 1024 + tid;                    // [0,8192) f32x4 slots
      int row = slot >> 7, u8 = slot & 127;
      f32x4 v = *(const f32x4*)(zp + (size_t)row * 512 + u8 * 4);
      f16x4 hv;
      #pragma unroll
      for (int r = 0; r < 4; ++r) hv[r] = (_Float16)(v[r] * 16.f);
      int gz = (u8 >> 1) ^ (row & 7);
      *(f16x4*)((char*)Az + row * 1024 + gz * 16 + (u8 & 1) * 8) = hv;
    }
  }
  if (tid < 1024) {
    bias1L[tid] = bias1[tid];
    cvecL[tid]  = cvec[tid];
  }
  __syncthreads();

  f32x4 acc1[4][2] = {};                            // GEMM1: [mt(row16)][nt(col16)]
  f32x4 acc2[4][2] = {};                            // GEMM2 accumulates across chunks
  float tr[4] = {0.f, 0.f, 0.f, 0.f};

  const char* azb   = (const char*)Az + m16 * 1024;
  const char* hbb   = (const char*)Hb + m16 * 1024;
  // 16-wave frag decode into the 8-wave slice layout:
  const char* wbase = (const char*)wp + (w >> 1) * 4096 + (w & 1) * 2048 + lane * 16;

  // weight prefetch stream: slice g fragments at wbase + g*32768 + nt*1024
  f16x8 cwA[2], cwB[2];
  cwA[0] = *(const f16x8*)(wbase);
  cwA[1] = *(const f16x8*)(wbase + 1024);

  for (int ch = 0; ch < 2; ++ch) {
    // ---- GEMM1: 16 k32-slices, h_pre chunk (cols ch*512..+512) ----
    for (int s2 = 0; s2 < 8; ++s2) {
      const int s = s2 * 2;
      const int g = ch * 32 + s;
      cwB[0] = *(const f16x8*)(wbase + (size_t)(g + 1) * 32768);
      cwB[1] = *(const f16x8*)(wbase + (size_t)(g + 1) * 32768 + 1024);
      {
        const int zg = ((s * 4 + q) ^ sw) << 4;
        f16x8 zf0 = *(const f16x8*)(azb + zg);
        f16x8 zf1 = *(const f16x8*)(azb + 16384 + zg);
        f16x8 zf2 = *(const f16x8*)(azb + 32768 + zg);
        f16x8 zf3 = *(const f16x8*)(azb + 49152 + zg);
        __builtin_amdgcn_s_setprio(1);
        acc1[0][0] = MFMA(cwA[0], zf0, acc1[0][0]);
        acc1[0][1] = MFMA(cwA[1], zf0, acc1[0][1]);
        acc1[1][0] = MFMA(cwA[0], zf1, acc1[1][0]);
        acc1[1][1] = MFMA(cwA[1], zf1, acc1[1][1]);
        acc1[2][0] = MFMA(cwA[0], zf2, acc1[2][0]);
        acc1[2][1] = MFMA(cwA[1], zf2, acc1[2][1]);
        acc1[3][0] = MFMA(cwA[0], zf3, acc1[3][0]);
        acc1[3][1] = MFMA(cwA[1], zf3, acc1[3][1]);
        __builtin_amdgcn_s_setprio(0);
      }
      {
        const int gn = (g + 2 > 63) ? 63 : (g + 2);
        cwA[0] = *(const f16x8*)(wbase + (size_t)gn * 32768);
        cwA[1] = *(const f16x8*)(wbase + (size_t)gn * 32768 + 1024);
      }
      {
        const int zg = (((s + 1) * 4 + q) ^ sw) << 4;
        f16x8 zf0 = *(const f16x8*)(azb + zg);
        f16x8 zf1 = *(const f16x8*)(azb + 16384 + zg);
        f16x8 zf2 = *(const f16x8*)(azb + 32768 + zg);
        f16x8 zf3 = *(const f16x8*)(azb + 49152 + zg);
        __builtin_amdgcn_s_setprio(1);
        acc1[0][0] = MFMA(cwB[0], zf0, acc1[0][0]);
        acc1[0][1] = MFMA(cwB[1], zf0, acc1[0][1]);
        acc1[1][0] = MFMA(cwB[0], zf1, acc1[1][0]);
        acc1[1][1] = MFMA(cwB[1], zf1, acc1[1][1]);
        acc1[2][0] = MFMA(cwB[0], zf2, acc1[2][0]);
        acc1[2][1] = MFMA(cwB[1], zf2, acc1[2][1]);
        acc1[3][0] = MFMA(cwB[0], zf3, acc1[3][0]);
        acc1[3][1] = MFMA(cwB[1], zf3, acc1[3][1]);
        __builtin_amdgcn_s_setprio(0);
      }
    }

    __syncthreads();   // A: all waves finished reading Hb in previous GEMM2

    // ---- chunk epilogue: bias+relu, trace, row-bucketed borderline, h -> Hb ----
    #pragma unroll
    for (int nt = 0; nt < 2; ++nt) {
      int colc = w * 32 + nt * 16 + q * 4;          // chunk-local col
      int col = ch * 512 + colc;
      f32x4 b4 = *(const f32x4*)&bias1L[col];
      f32x4 c4 = *(const f32x4*)&cvecL[col];
      #pragma unroll
      for (int mt = 0; mt < 4; ++mt) {
        int row = mt * 16 + m16;
        f16x4 hv;
        #pragma unroll
        for (int r = 0; r < 4; ++r) {
          float hp = acc1[mt][nt][r] * (1.f / 1024.f) + b4[r];
          hv[r] = (_Float16)(hp > 0.f ? hp : 0.f);
          if (hp > 0.f) tr[mt] += c4[r];
          if (__builtin_fabsf(hp) < DELTA) {
            uint32_t e = (uint32_t)(col + r) | (hp > 0.f ? 0x80000000u : 0u);
            uint32_t bi = atomicAdd(&rbcnt[row], 1u);   // LDS atomic: cheap
            if (bi < RCAP) rbuck[row][bi] = e;
            else {
              uint32_t oi = atomicAdd(&ovfcnt, 1u);
              if (oi < OCAP) ovf[oi] = ((uint32_t)row << 10) | e;
            }
          }
        }
        int gg = (colc >> 3) ^ (row & 7);
        *(f16x4*)((char*)Hb + row * 1024 + gg * 16 + (q & 1) * 8) = hv;
        acc1[mt][nt] = (f32x4){0.f, 0.f, 0.f, 0.f};
      }
    }

    __syncthreads();   // B: Hb(ch) visible to all waves

    // ---- GEMM2: 16 k32-slices, dz += h_chunk @ W2[:, ch*512..]^T ----
    for (int t2 = 0; t2 < 8; ++t2) {
      const int t = t2 * 2;
      const int g = ch * 32 + 16 + t;
      cwB[0] = *(const f16x8*)(wbase + (size_t)(g + 1) * 32768);
      cwB[1] = *(const f16x8*)(wbase + (size_t)(g + 1) * 32768 + 1024);
      {
        const int hg = ((t * 4 + q) ^ sw) << 4;
        f16x8 hf0 = *(const f16x8*)(hbb + hg);
        f16x8 hf1 = *(const f16x8*)(hbb + 16384 + hg);
        f16x8 hf2 = *(const f16x8*)(hbb + 32768 + hg);
        f16x8 hf3 = *(const f16x8*)(hbb + 49152 + hg);
        __builtin_amdgcn_s_setprio(1);
        acc2[0][0] = MFMA(cwA[0], hf0, acc2[0][0]);
        acc2[0][1] = MFMA(cwA[1], hf0, acc2[0][1]);
        acc2[1][0] = MFMA(cwA[0], hf1, acc2[1][0]);
        acc2[1][1] = MFMA(cwA[1], hf1, acc2[1][1]);
        acc2[2][0] = MFMA(cwA[0], hf2, acc2[2][0]);
        acc2[2][1] = MFMA(cwA[1], hf2, acc2[2][1]);
        acc2[3][0] = MFMA(cwA[0], hf3, acc2[3][0]);
        acc2[3][1] = MFMA(cwA[1], hf3, acc2[3][1]);
        __builtin_amdgcn_s_setprio(0);
      }
      {
        const int gn = (g + 2 > 63) ? 63 : (g + 2);
        cwA[0] = *(const f16x8*)(wbase + (size_t)gn * 32768);
        cwA[1] = *(const f16x8*)(wbase + (size_t)gn * 32768 + 1024);
      }
      {
        const int hg = (((t + 1) * 4 + q) ^ sw) << 4;
        f16x8 hf0 = *(const f16x8*)(hbb + hg);
        f16x8 hf1 = *(const f16x8*)(hbb + 16384 + hg);
        f16x8 hf2 = *(const f16x8*)(hbb + 32768 + hg);
        f16x8 hf3 = *(const f16x8*)(hbb + 49152 + hg);
        __builtin_amdgcn_s_setprio(1);
        acc2[0][0] = MFMA(cwB[0], hf0, acc2[0][0]);
        acc2[0][1] = MFMA(cwB[1], hf0, acc2[0][1]);
        acc2[1][0] = MFMA(cwB[0], hf1, acc2[1][0]);
        acc2[1][1] = MFMA(cwB[1], hf1, acc2[1][1]);
        acc2[2][0] = MFMA(cwB[0], hf2, acc2[2][0]);
        acc2[2][1] = MFMA(cwB[1], hf2, acc2[2][1]);
        acc2[3][0] = MFMA(cwB[0], hf3, acc2[3][0]);
        acc2[3][1] = MFMA(cwB[1], hf3, acc2[3][1]);
        __builtin_amdgcn_s_setprio(0);
      }
    }
  }

  // ---- dz store: +bias2, f32x4 (4 consecutive cols per thread) ----
  #pragma unroll
  for (int mt = 0; mt < 4; ++mt) {
    int row = bm * 64 + mt * 16 + m16;
    #pragma unroll
    for (int nt = 0; nt < 2; ++nt) {
      int col = w * 32 + nt * 16 + q * 4;
      f32x4 b2v = *(const f32x4*)(bias2 + col);
      *(f32x4*)(out + (size_t)row * 512 + col) = acc2[mt][nt] + b2v;
    }
  }

  // ---- trace: block-local partials to LDS ----
  #pragma unroll
  for (int mt = 0; mt < 4; ++mt) {
    tr[mt] += __shfl_xor(tr[mt], 16);
    tr[mt] += __shfl_xor(tr[mt], 32);
  }
  if (q == 0) {
    #pragma unroll
    for (int mt = 0; mt < 4; ++mt) redbuf[w][mt * 16 + m16] = tr[mt];
  }
  __syncthreads();   // redbuf + rbuck/rbcnt/ovf final

  // ---- in-block fixup: wave w owns rows [w*4, +4); 2-deep pipelined W1 cols ----
  #pragma unroll 1
  for (int r4 = 0; r4 < 4; ++r4) {
    int row = w * 4 + r4;
    uint32_t cnt = rbcnt[row];
    if (cnt > RCAP) cnt = RCAP;
    float corr = 0.f;
    if (cnt) {
      const float* zr = z + ((size_t)(bm * 64 + row)) * 512;
      float zv[8];
      #pragma unroll
      for (int it = 0; it < 8; ++it) zv[it] = zr[it * 64 + lane];
      uint32_t en = rbuck[row][0];
      const float* wc0 = W1f + (size_t)(en & 1023u) * 513;
      float wv[8];
      #pragma unroll
      for (int it = 0; it < 8; ++it) wv[it] = wc0[it * 64 + lane];
      for (uint32_t e = 0; e < cnt; ++e) {
        int col  = (int)(en & 1023u);
        int oldm = (int)(en >> 31);
        float wn[8];
        if (e + 1 < cnt) {                          // prefetch next column
          en = rbuck[row][e + 1];
          const float* wcn = W1f + (size_t)(en & 1023u) * 513;
          #pragma unroll
          for (int it = 0; it < 8; ++it) wn[it] = wcn[it * 64 + lane];
        }
        float s = 0.f;
        #pragma unroll
        for (int it = 0; it < 8; ++it) s += zv[it] * wv[it];
        #pragma unroll
        for (int off = 32; off > 0; off >>= 1) s += __shfl_xor(s, off);
        float hp = s + bias1L[col];
        int newm = hp > 0.f ? 1 : 0;
        if (newm != oldm) corr += oldm ? cvecL[col] : -cvecL[col];
        #pragma unroll
        for (int it = 0; it < 8; ++it) wv[it] = wn[it];
      }
    }
    if (lane == 0) fixv[row] = corr;               // wave-owned: plain store
  }
  // overflow entries (statistically never; correctness safety net)
  {
    uint32_t on = ovfcnt;
    if (on > OCAP) on = OCAP;
    for (uint32_t i = w; i < on; i += 16) {
      uint32_t e = ovf[i];
      int row  = (int)((e >> 10) & 63u);
      int col  = (int)(e & 1023u);
      int oldm = (int)(e >> 31);
      const float* zr = z + ((size_t)(bm * 64 + row)) * 512;
      const float* wc = W1f + (size_t)col * 513;
      float s = 0.f;
      #pragma unroll
      for (int it = 0; it < 8; ++it) {
        int k = it * 64 + lane;
        s += zr[k] * wc[k];
      }
      #pragma unroll
      for (int off = 32; off > 0; off >>= 1) s += __shfl_xor(s, off);
      if (lane == 0) {
        float hp = s + bias1L[col];
        int newm = hp > 0.f ? 1 : 0;
        if (newm != oldm) atomicAdd(&fixo[row], oldm ? cvecL[col] : -cvecL[col]);
      }
    }
  }
  __syncthreads();

  // ---- final dlogp: -(trace) + corrections, deterministic store ----
  if (tid < 64) {
    float s = 0.f;
    #pragma unroll
    for (int ww = 0; ww < 16; ++ww) s += redbuf[ww][tid];
    dlogp[bm * 64 + tid] = -s + fixv[tid] + fixo[tid];
  }
}

// ---------------- launcher ----------------
extern "C" void kernel_launch(void* const* d_in, const int* in_sizes, int n_in,
                              void* d_out, int out_size, void* d_ws, size_t ws_size,
                              hipStream_t stream) {
  const float* t  = (const float*)d_in[0];
  const float* z  = (const float*)d_in[1];
  // d_in[2] = logp_z, unused
  const float* W1 = (const float*)d_in[3];
  const float* b1 = (const float*)d_in[4];
  const float* W2 = (const float*)d_in[5];
  const float* b2 = (const float*)d_in[6];

  float* out   = (float*)d_out;
  float* dlogp = out + (size_t)B_ * D_;

  char* ws = (char*)d_ws;
  _Float16* wp    = (_Float16*)ws; ws += (size_t)64 * 32768;     // 2 MB permuted weights
  float*    bias1 = (float*)ws;    ws += 1024 * 4;
  float*    bias2 = (float*)ws;    ws += 512 * 4;
  float*    cvec  = (float*)ws;    ws += 1024 * 4;

  prep_w<<<772, 256, 0, stream>>>(t, W1, b1, W2, b2, wp, bias1, bias2, cvec);
  fused_kernel<<<256, 1024, 0, stream>>>(z, wp, W1, bias1, bias2, cvec, out, dlogp);
}

// Round 10
// 150.645 us; speedup vs baseline: 1.0810x; 1.0591x over previous
//
#include <hip/hip_runtime.h>
#include <stdint.h>

#define B_   16384
#define D_   512
#define N1_  1024   // 2D
#define K1_  512    // D
#define N2_  512
#define K2_  1024

#define DELTA     4e-3f
#define RCAP      16u          // per-row bucket capacity (Poisson mean 3.3)
#define OCAP      32u          // overflow list capacity

typedef _Float16 f16x8 __attribute__((ext_vector_type(8)));
typedef _Float16 f16x4 __attribute__((ext_vector_type(4)));
typedef float    f32x4 __attribute__((ext_vector_type(4)));

#define MFMA(a, b, c) __builtin_amdgcn_mfma_f32_16x16x32_f16(a, b, c, 0, 0, 0)

// ---------------- prep: frag-major permuted weights + biases + cvec ----------------
// wp: 64 slices x 32 KB. Slice g (ch=g>>5, ph=g&31): ph<16 -> W1 cols ch*512..,
// k=ph*32 (x64 scale); ph>=16 -> W2 all 512 dz-cols, k=ch*512+(ph-16)*32.
// Slice bytes: [wave w: 4KB][nt 0..3: 1KB][lane: 16B] = the exact A-operand
// fragment each lane consumes -> coalesced 16B/lane loads, weights never in LDS.
__global__ __launch_bounds__(256) void prep_w(
    const float* __restrict__ t,
    const float* __restrict__ W1, const float* __restrict__ b1,
    const float* __restrict__ W2, const float* __restrict__ b2,
    _Float16* __restrict__ wp,
    float* __restrict__ bias1, float* __restrict__ bias2,
    float* __restrict__ cvec) {
  int blk = blockIdx.x, tid = threadIdx.x;
  if (blk < 512) {                                  // 131072 granules of 16 B
    int idx = blk * 256 + tid;
    int g = idx >> 11, rem = idx & 2047;
    int w = rem >> 8, nt = (rem >> 6) & 3, lane = rem & 63;
    int m16 = lane & 15, q = lane >> 4;
    int ch = g >> 5, ph = g & 31;
    const float* src;
    float scale;
    if (ph < 16) {                                  // W1 frag: m=h-col, k
      int col = ch * 512 + w * 64 + nt * 16 + m16;
      int k = ph * 32 + q * 8;
      src = W1 + (size_t)col * 513 + k;
      scale = 64.f;
    } else {                                        // W2 frag: m=dz-col, k=h-col
      int col = w * 64 + nt * 16 + m16;
      int k = ch * 512 + (ph - 16) * 32 + q * 8;
      src = W2 + (size_t)col * 1025 + k;
      scale = 1.f;
    }
    f16x8 hv;
    #pragma unroll
    for (int e = 0; e < 8; ++e) hv[e] = (_Float16)(src[e] * scale);
    *(f16x8*)(wp + (size_t)idx * 8) = hv;
  } else if (blk < 516) {                           // biases
    int j = (blk - 512) * 256 + tid;                // [0, 1024)
    float t0 = t[0];
    bias1[j] = b1[j] + t0 * W1[(size_t)j * 513 + 512];
    if (j < 512) bias2[j] = b2[j] + t0 * W2[(size_t)j * 1025 + 1024];
  } else {                                          // c[j] = sum_k W2[k,j]*W1[j,k]
    int wave = tid >> 6, lane = tid & 63;
    int j = (blk - 516) * 4 + wave;                 // [0, 1024)
    float s = 0.f;
    #pragma unroll
    for (int kk = 0; kk < 8; ++kk) {
      int k = lane + kk * 64;
      s += W2[(size_t)k * 1025 + j] * W1[(size_t)j * 513 + k];
    }
    #pragma unroll
    for (int off = 32; off > 0; off >>= 1) s += __shfl_xor(s, off);
    if (lane == 0) cvec[j] = s;
  }
}

// ---------------- fused: 64-row block, 8 waves, half-slice pipelined core ----------------
// Block = 64 z-rows, 512 threads (8 waves, 2/SIMD), grid 256 (1 block/CU).
// Wave w owns cols [w*64,+64); acc = 128 AGPR. Weights: double-buffered reg stream.
// NEW vs r7: each slice's 16 MFMAs split into two 8-MFMA halves (mt 0-1 / 2-3);
// the NEXT half's 2 zf ds_reads are issued before the CURRENT half's MFMAs
// (register-neutral: cur+next = 16 VGPRs, same as r7's zf[4]) so LDS latency
// hides under MFMA issue instead of serializing per slice.
// Tail: zv-once-per-row + PAIR-parallel entries (half-wave each, one shfl(32) merge).

__global__ __launch_bounds__(512) void fused_kernel(
    const float* __restrict__ z, const _Float16* __restrict__ wp,
    const float* __restrict__ W1f,
    const float* __restrict__ bias1, const float* __restrict__ bias2,
    const float* __restrict__ cvec,
    float* __restrict__ out, float* __restrict__ dlogp) {
  __shared__ __align__(16) _Float16 Az[64 * 512];   // 64 KB swizzled z (f16 x16)
  __shared__ __align__(16) _Float16 Hb[64 * 512];   // 64 KB swizzled h chunk
  __shared__ __align__(16) float bias1L[1024];      // 4 KB
  __shared__ __align__(16) float cvecL[1024];       // 4 KB
  __shared__ uint32_t rbuck[64][RCAP];              // 4 KB row-bucketed borderline
  __shared__ uint32_t rbcnt[64];                    // 256 B
  __shared__ uint32_t ovf[OCAP];                    // 128 B
  __shared__ float redbuf[8][64];                   // 2 KB
  __shared__ float fixv[64];                        // wave-owned corrections
  __shared__ float fixo[64];                        // overflow corrections
  __shared__ uint32_t ovfcnt;                       // ~143 KB total

  const int tid  = threadIdx.x;
  const int lane = tid & 63, w = tid >> 6;          // wave 0..7
  const int q    = lane >> 4, m16 = lane & 15;
  const int sw   = m16 & 7;
  const int bm   = blockIdx.x;                      // 256 blocks x 64 rows

  if (tid < 64) { rbcnt[tid] = 0; fixo[tid] = 0.f; }
  if (tid == 0) ovfcnt = 0;

  // ---- stage z (f32 -> f16 x16) into swizzled Az: 64x512 ----
  {
    const float* zp = z + (size_t)bm * 64 * 512;
    #pragma unroll
    for (int i = 0; i < 16; ++i) {
      int slot = i * 512 + tid;
      int row = slot >> 7, u8 = slot & 127;
      f32x4 v = *(const f32x4*)(zp + (size_t)row * 512 + u8 * 4);
      f16x4 hv;
      #pragma unroll
      for (int r = 0; r < 4; ++r) hv[r] = (_Float16)(v[r] * 16.f);
      int gz = (u8 >> 1) ^ (row & 7);
      *(f16x4*)((char*)Az + row * 1024 + gz * 16 + (u8 & 1) * 8) = hv;
    }
  }
  for (int i = tid; i < 1024; i += 512) {
    bias1L[i] = bias1[i];
    cvecL[i]  = cvec[i];
  }
  __syncthreads();

  f32x4 acc1[4][4] = {};                            // GEMM1: [mt(row16)][nt(col16)]
  f32x4 acc2[4][4] = {};                            // GEMM2 accumulates across chunks
  float tr[4] = {0.f, 0.f, 0.f, 0.f};

  const char* azb   = (const char*)Az + m16 * 1024;
  const char* hbb   = (const char*)Hb + m16 * 1024;
  const char* wbase = (const char*)wp + w * 4096 + lane * 16;

  f16x8 cwA[4], cwB[4];
  f16x8 zc0, zc1, zn0, zn1;                         // half-slice zf ping-pong
  {
    const char* wb = wbase;                         // slice 0
    cwA[0] = *(const f16x8*)(wb);
    cwA[1] = *(const f16x8*)(wb + 1024);
    cwA[2] = *(const f16x8*)(wb + 2048);
    cwA[3] = *(const f16x8*)(wb + 3072);
  }

  for (int ch = 0; ch < 2; ++ch) {
    // ---- GEMM1: 16 k32-slices; half-slice zf pipeline ----
    {
      const int zg = (q ^ sw) << 4;                 // (s=0, half0)
      zc0 = *(const f16x8*)(azb + zg);
      zc1 = *(const f16x8*)(azb + 16384 + zg);
    }
    for (int s2 = 0; s2 < 8; ++s2) {
      const int s = s2 * 2;
      const int g = ch * 32 + s;
      {
        const char* wb = wbase + (size_t)(g + 1) * 32768;
        cwB[0] = *(const f16x8*)(wb);
        cwB[1] = *(const f16x8*)(wb + 1024);
        cwB[2] = *(const f16x8*)(wb + 2048);
        cwB[3] = *(const f16x8*)(wb + 3072);
      }
      {   // prefetch (s, half1); compute (s, half0) with cwA
        const int zg = ((s * 4 + q) ^ sw) << 4;
        zn0 = *(const f16x8*)(azb + 32768 + zg);
        zn1 = *(const f16x8*)(azb + 49152 + zg);
        __builtin_amdgcn_s_setprio(1);
        acc1[0][0] = MFMA(cwA[0], zc0, acc1[0][0]);
        acc1[0][1] = MFMA(cwA[1], zc0, acc1[0][1]);
        acc1[0][2] = MFMA(cwA[2], zc0, acc1[0][2]);
        acc1[0][3] = MFMA(cwA[3], zc0, acc1[0][3]);
        acc1[1][0] = MFMA(cwA[0], zc1, acc1[1][0]);
        acc1[1][1] = MFMA(cwA[1], zc1, acc1[1][1]);
        acc1[1][2] = MFMA(cwA[2], zc1, acc1[1][2]);
        acc1[1][3] = MFMA(cwA[3], zc1, acc1[1][3]);
        __builtin_amdgcn_s_setprio(0);
      }
      {   // prefetch (s+1, half0); compute (s, half1) with cwA
        const int zg = (((s + 1) * 4 + q) ^ sw) << 4;
        zc0 = *(const f16x8*)(azb + zg);
        zc1 = *(const f16x8*)(azb + 16384 + zg);
        __builtin_amdgcn_s_setprio(1);
        acc1[2][0] = MFMA(cwA[0], zn0, acc1[2][0]);
        acc1[2][1] = MFMA(cwA[1], zn0, acc1[2][1]);
        acc1[2][2] = MFMA(cwA[2], zn0, acc1[2][2]);
        acc1[2][3] = MFMA(cwA[3], zn0, acc1[2][3]);
        acc1[3][0] = MFMA(cwA[0], zn1, acc1[3][0]);
        acc1[3][1] = MFMA(cwA[1], zn1, acc1[3][1]);
        acc1[3][2] = MFMA(cwA[2], zn1, acc1[3][2]);
        acc1[3][3] = MFMA(cwA[3], zn1, acc1[3][3]);
        __builtin_amdgcn_s_setprio(0);
      }
      {
        const int gn = (g + 2 > 63) ? 63 : (g + 2);
        const char* wb = wbase + (size_t)gn * 32768;
        cwA[0] = *(const f16x8*)(wb);
        cwA[1] = *(const f16x8*)(wb + 1024);
        cwA[2] = *(const f16x8*)(wb + 2048);
        cwA[3] = *(const f16x8*)(wb + 3072);
      }
      {   // prefetch (s+1, half1); compute (s+1, half0) with cwB
        const int zg = (((s + 1) * 4 + q) ^ sw) << 4;
        zn0 = *(const f16x8*)(azb + 32768 + zg);
        zn1 = *(const f16x8*)(azb + 49152 + zg);
        __builtin_amdgcn_s_setprio(1);
        acc1[0][0] = MFMA(cwB[0], zc0, acc1[0][0]);
        acc1[0][1] = MFMA(cwB[1], zc0, acc1[0][1]);
        acc1[0][2] = MFMA(cwB[2], zc0, acc1[0][2]);
        acc1[0][3] = MFMA(cwB[3], zc0, acc1[0][3]);
        acc1[1][0] = MFMA(cwB[0], zc1, acc1[1][0]);
        acc1[1][1] = MFMA(cwB[1], zc1, acc1[1][1]);
        acc1[1][2] = MFMA(cwB[2], zc1, acc1[1][2]);
        acc1[1][3] = MFMA(cwB[3], zc1, acc1[1][3]);
        __builtin_amdgcn_s_setprio(0);
      }
      {   // prefetch (s+2, half0) [clamped]; compute (s+1, half1) with cwB
        const int sn = (s + 2 > 15) ? 15 : (s + 2);
        const int zg = ((sn * 4 + q) ^ sw) << 4;
        zc0 = *(const f16x8*)(azb + zg);
        zc1 = *(const f16x8*)(azb + 16384 + zg);
        __builtin_amdgcn_s_setprio(1);
        acc1[2][0] = MFMA(cwB[0], zn0, acc1[2][0]);
        acc1[2][1] = MFMA(cwB[1], zn0, acc1[2][1]);
        acc1[2][2] = MFMA(cwB[2], zn0, acc1[2][2]);
        acc1[2][3] = MFMA(cwB[3], zn0, acc1[2][3]);
        acc1[3][0] = MFMA(cwB[0], zn1, acc1[3][0]);
        acc1[3][1] = MFMA(cwB[1], zn1, acc1[3][1]);
        acc1[3][2] = MFMA(cwB[2], zn1, acc1[3][2]);
        acc1[3][3] = MFMA(cwB[3], zn1, acc1[3][3]);
        __builtin_amdgcn_s_setprio(0);
      }
    }

    __syncthreads();   // A: all waves finished reading Hb in previous GEMM2

    // ---- chunk epilogue: bias+relu, trace, row-bucketed borderline, h -> Hb ----
    #pragma unroll
    for (int nt = 0; nt < 4; ++nt) {
      int colc = w * 64 + nt * 16 + q * 4;          // chunk-local col
      int col = ch * 512 + colc;
      f32x4 b4 = *(const f32x4*)&bias1L[col];
      f32x4 c4 = *(const f32x4*)&cvecL[col];
      #pragma unroll
      for (int mt = 0; mt < 4; ++mt) {
        int row = mt * 16 + m16;
        f16x4 hv;
        #pragma unroll
        for (int r = 0; r < 4; ++r) {
          float hp = acc1[mt][nt][r] * (1.f / 1024.f) + b4[r];
          hv[r] = (_Float16)(hp > 0.f ? hp : 0.f);
          if (hp > 0.f) tr[mt] += c4[r];
          if (__builtin_fabsf(hp) < DELTA) {
            uint32_t e = (uint32_t)(col + r) | (hp > 0.f ? 0x80000000u : 0u);
            uint32_t bi = atomicAdd(&rbcnt[row], 1u);   // LDS atomic: cheap
            if (bi < RCAP) rbuck[row][bi] = e;
            else {
              uint32_t oi = atomicAdd(&ovfcnt, 1u);
              if (oi < OCAP) ovf[oi] = ((uint32_t)row << 10) | e;
            }
          }
        }
        int gg = (colc >> 3) ^ (row & 7);
        *(f16x4*)((char*)Hb + row * 1024 + gg * 16 + (q & 1) * 8) = hv;
        acc1[mt][nt] = (f32x4){0.f, 0.f, 0.f, 0.f};
      }
    }

    __syncthreads();   // B: Hb(ch) visible to all waves

    // ---- GEMM2: 16 k32-slices, dz += h_chunk @ W2[:, ch*512..]^T ----
    {
      const int zg = (q ^ sw) << 4;                 // (t=0, half0)
      zc0 = *(const f16x8*)(hbb + zg);
      zc1 = *(const f16x8*)(hbb + 16384 + zg);
    }
    for (int t2 = 0; t2 < 8; ++t2) {
      const int t = t2 * 2;
      const int g = ch * 32 + 16 + t;
      {
        const char* wb = wbase + (size_t)(g + 1) * 32768;
        cwB[0] = *(const f16x8*)(wb);
        cwB[1] = *(const f16x8*)(wb + 1024);
        cwB[2] = *(const f16x8*)(wb + 2048);
        cwB[3] = *(const f16x8*)(wb + 3072);
      }
      {   // prefetch (t, half1); compute (t, half0) with cwA
        const int zg = ((t * 4 + q) ^ sw) << 4;
        zn0 = *(const f16x8*)(hbb + 32768 + zg);
        zn1 = *(const f16x8*)(hbb + 49152 + zg);
        __builtin_amdgcn_s_setprio(1);
        acc2[0][0] = MFMA(cwA[0], zc0, acc2[0][0]);
        acc2[0][1] = MFMA(cwA[1], zc0, acc2[0][1]);
        acc2[0][2] = MFMA(cwA[2], zc0, acc2[0][2]);
        acc2[0][3] = MFMA(cwA[3], zc0, acc2[0][3]);
        acc2[1][0] = MFMA(cwA[0], zc1, acc2[1][0]);
        acc2[1][1] = MFMA(cwA[1], zc1, acc2[1][1]);
        acc2[1][2] = MFMA(cwA[2], zc1, acc2[1][2]);
        acc2[1][3] = MFMA(cwA[3], zc1, acc2[1][3]);
        __builtin_amdgcn_s_setprio(0);
      }
      {   // prefetch (t+1, half0); compute (t, half1) with cwA
        const int zg = (((t + 1) * 4 + q) ^ sw) << 4;
        zc0 = *(const f16x8*)(hbb + zg);
        zc1 = *(const f16x8*)(hbb + 16384 + zg);
        __builtin_amdgcn_s_setprio(1);
        acc2[2][0] = MFMA(cwA[0], zn0, acc2[2][0]);
        acc2[2][1] = MFMA(cwA[1], zn0, acc2[2][1]);
        acc2[2][2] = MFMA(cwA[2], zn0, acc2[2][2]);
        acc2[2][3] = MFMA(cwA[3], zn0, acc2[2][3]);
        acc2[3][0] = MFMA(cwA[0], zn1, acc2[3][0]);
        acc2[3][1] = MFMA(cwA[1], zn1, acc2[3][1]);
        acc2[3][2] = MFMA(cwA[2], zn1, acc2[3][2]);
        acc2[3][3] = MFMA(cwA[3], zn1, acc2[3][3]);
        __builtin_amdgcn_s_setprio(0);
      }
      {
        const int gn = (g + 2 > 63) ? 63 : (g + 2);
        const char* wb = wbase + (size_t)gn * 32768;
        cwA[0] = *(const f16x8*)(wb);
        cwA[1] = *(const f16x8*)(wb + 1024);
        cwA[2] = *(const f16x8*)(wb + 2048);
        cwA[3] = *(const f16x8*)(wb + 3072);
      }
      {   // prefetch (t+1, half1); compute (t+1, half0) with cwB
        const int zg = (((t + 1) * 4 + q) ^ sw) << 4;
        zn0 = *(const f16x8*)(hbb + 32768 + zg);
        zn1 = *(const f16x8*)(hbb + 49152 + zg);
        __builtin_amdgcn_s_setprio(1);
        acc2[0][0] = MFMA(cwB[0], zc0, acc2[0][0]);
        acc2[0][1] = MFMA(cwB[1], zc0, acc2[0][1]);
        acc2[0][2] = MFMA(cwB[2], zc0, acc2[0][2]);
        acc2[0][3] = MFMA(cwB[3], zc0, acc2[0][3]);
        acc2[1][0] = MFMA(cwB[0], zc1, acc2[1][0]);
        acc2[1][1] = MFMA(cwB[1], zc1, acc2[1][1]);
        acc2[1][2] = MFMA(cwB[2], zc1, acc2[1][2]);
        acc2[1][3] = MFMA(cwB[3], zc1, acc2[1][3]);
        __builtin_amdgcn_s_setprio(0);
      }
      {   // prefetch (t+2, half0) [clamped]; compute (t+1, half1) with cwB
        const int tn = (t + 2 > 15) ? 15 : (t + 2);
        const int zg = ((tn * 4 + q) ^ sw) << 4;
        zc0 = *(const f16x8*)(hbb + zg);
        zc1 = *(const f16x8*)(hbb + 16384 + zg);
        __builtin_amdgcn_s_setprio(1);
        acc2[2][0] = MFMA(cwB[0], zn0, acc2[2][0]);
        acc2[2][1] = MFMA(cwB[1], zn0, acc2[2][1]);
        acc2[2][2] = MFMA(cwB[2], zn0, acc2[2][2]);
        acc2[2][3] = MFMA(cwB[3], zn0, acc2[2][3]);
        acc2[3][0] = MFMA(cwB[0], zn1, acc2[3][0]);
        acc2[3][1] = MFMA(cwB[1], zn1, acc2[3][1]);
        acc2[3][2] = MFMA(cwB[2], zn1, acc2[3][2]);
        acc2[3][3] = MFMA(cwB[3], zn1, acc2[3][3]);
        __builtin_amdgcn_s_setprio(0);
      }
    }
  }

  // ---- dz store: +bias2, f32x4 (4 consecutive cols per thread) ----
  #pragma unroll
  for (int mt = 0; mt < 4; ++mt) {
    int row = bm * 64 + mt * 16 + m16;
    #pragma unroll
    for (int nt = 0; nt < 4; ++nt) {
      int col = w * 64 + nt * 16 + q * 4;
      f32x4 b2v = *(const f32x4*)(bias2 + col);
      *(f32x4*)(out + (size_t)row * 512 + col) = acc2[mt][nt] + b2v;
    }
  }

  // ---- trace: block-local partials to LDS ----
  #pragma unroll
  for (int mt = 0; mt < 4; ++mt) {
    tr[mt] += __shfl_xor(tr[mt], 16);
    tr[mt] += __shfl_xor(tr[mt], 32);
  }
  if (q == 0) {
    #pragma unroll
    for (int mt = 0; mt < 4; ++mt) redbuf[w][mt * 16 + m16] = tr[mt];
  }
  __syncthreads();   // redbuf + rbuck/rbcnt/ovf final

  // ---- in-block fixup: wave w owns rows [w*8,+8); zv once/row; PAIR-parallel ----
  {
    const int hlane = lane & 31;                    // lane within half-wave
    const int half  = lane >> 5;                    // 0 or 1
    #pragma unroll 1
    for (int r8 = 0; r8 < 8; ++r8) {
      int row = w * 8 + r8;
      uint32_t cnt = rbcnt[row];
      if (cnt > RCAP) cnt = RCAP;
      float corr = 0.f;
      if (cnt) {
        const float* zr = z + ((size_t)(bm * 64 + row)) * 512;
        float zv[16];
        #pragma unroll
        for (int it = 0; it < 16; ++it) zv[it] = zr[it * 32 + hlane];
        for (uint32_t e = 0; e < cnt; e += 2) {
          uint32_t idx = e + (uint32_t)half;
          int act = idx < cnt;
          uint32_t en = rbuck[row][act ? idx : e];
          int col  = (int)(en & 1023u);
          int oldm = (int)(en >> 31);
          const float* wc = W1f + (size_t)col * 513;
          float s = 0.f;
          #pragma unroll
          for (int it = 0; it < 16; ++it) s += zv[it] * wc[it * 32 + hlane];
          #pragma unroll
          for (int off = 16; off > 0; off >>= 1) s += __shfl_xor(s, off);
          float hp = s + bias1L[col];
          int newm = hp > 0.f ? 1 : 0;
          float delta = (act && newm != oldm) ? (oldm ? cvecL[col] : -cvecL[col]) : 0.f;
          delta += __shfl_xor(delta, 32);           // merge the two halves
          corr += delta;                            // valid in lane 0
        }
      }
      if (lane == 0) fixv[row] = corr;              // wave-owned: plain store
    }
  }
  // overflow entries (statistically never; correctness safety net)
  {
    uint32_t on = ovfcnt;
    if (on > OCAP) on = OCAP;
    for (uint32_t i = w; i < on; i += 8) {
      uint32_t e = ovf[i];
      int row  = (int)((e >> 10) & 63u);
      int col  = (int)(e & 1023u);
      int oldm = (int)(e >> 31);
      const float* zr = z + ((size_t)(bm * 64 + row)) * 512;
      const float* wc = W1f + (size_t)col * 513;
      float s = 0.f;
      #pragma unroll
      for (int it = 0; it < 8; ++it) {
        int k = it * 64 + lane;
        s += zr[k] * wc[k];
      }
      #pragma unroll
      for (int off = 32; off > 0; off >>= 1) s += __shfl_xor(s, off);
      if (lane == 0) {
        float hp = s + bias1L[col];
        int newm = hp > 0.f ? 1 : 0;
        if (newm != oldm) atomicAdd(&fixo[row], oldm ? cvecL[col] : -cvecL[col]);
      }
    }
  }
  __syncthreads();

  // ---- final dlogp: -(trace) + corrections, deterministic store ----
  if (tid < 64) {
    float s = 0.f;
    #pragma unroll
    for (int ww = 0; ww < 8; ++ww) s += redbuf[ww][tid];
    dlogp[bm * 64 + tid] = -s + fixv[tid] + fixo[tid];
  }
}

// ---------------- launcher ----------------
extern "C" void kernel_launch(void* const* d_in, const int* in_sizes, int n_in,
                              void* d_out, int out_size, void* d_ws, size_t ws_size,
                              hipStream_t stream) {
  const float* t  = (const float*)d_in[0];
  const float* z  = (const float*)d_in[1];
  // d_in[2] = logp_z, unused
  const float* W1 = (const float*)d_in[3];
  const float* b1 = (const float*)d_in[4];
  const float* W2 = (const float*)d_in[5];
  const float* b2 = (const float*)d_in[6];

  float* out   = (float*)d_out;
  float* dlogp = out + (size_t)B_ * D_;

  char* ws = (char*)d_ws;
  _Float16* wp    = (_Float16*)ws; ws += (size_t)64 * 32768;     // 2 MB permuted weights
  float*    bias1 = (float*)ws;    ws += 1024 * 4;
  float*    bias2 = (float*)ws;    ws += 512 * 4;
  float*    cvec  = (float*)ws;    ws += 1024 * 4;

  prep_w<<<772, 256, 0, stream>>>(t, W1, b1, W2, b2, wp, bias1, bias2, cvec);
  fused_kernel<<<256, 512, 0, stream>>>(z, wp, W1, bias1, bias2, cvec, out, dlogp);
}

// Round 11
// 149.098 us; speedup vs baseline: 1.0922x; 1.0104x over previous
//
#include <hip/hip_runtime.h>
#include <stdint.h>

#define B_   16384
#define D_   512
#define N1_  1024   // 2D
#define K1_  512    // D
#define N2_  512
#define K2_  1024

#define DELTA     4e-3f
#define RCAP      16u          // per-row bucket capacity (Poisson mean 3.3)
#define OCAP      32u          // overflow list capacity

typedef _Float16 f16x8 __attribute__((ext_vector_type(8)));
typedef _Float16 f16x4 __attribute__((ext_vector_type(4)));
typedef float    f32x4 __attribute__((ext_vector_type(4)));

#define MFMA(a, b, c) __builtin_amdgcn_mfma_f32_16x16x32_f16(a, b, c, 0, 0, 0)

// ---------------- prep: frag-major permuted weights + biases + cvec ----------------
// wp: 64 slices x 32 KB. Slice g (ch=g>>5, ph=g&31): ph<16 -> W1 cols ch*512..,
// k=ph*32 (x64 scale); ph>=16 -> W2 all 512 dz-cols, k=ch*512+(ph-16)*32.
// Slice bytes: [wave w: 4KB][nt 0..3: 1KB][lane: 16B] = the exact A-operand
// fragment each lane consumes -> coalesced 16B/lane loads, weights never in LDS.
__global__ __launch_bounds__(256) void prep_w(
    const float* __restrict__ t,
    const float* __restrict__ W1, const float* __restrict__ b1,
    const float* __restrict__ W2, const float* __restrict__ b2,
    _Float16* __restrict__ wp,
    float* __restrict__ bias1, float* __restrict__ bias2,
    float* __restrict__ cvec) {
  int blk = blockIdx.x, tid = threadIdx.x;
  if (blk < 512) {                                  // 131072 granules of 16 B
    int idx = blk * 256 + tid;
    int g = idx >> 11, rem = idx & 2047;
    int w = rem >> 8, nt = (rem >> 6) & 3, lane = rem & 63;
    int m16 = lane & 15, q = lane >> 4;
    int ch = g >> 5, ph = g & 31;
    const float* src;
    float scale;
    if (ph < 16) {                                  // W1 frag: m=h-col, k
      int col = ch * 512 + w * 64 + nt * 16 + m16;
      int k = ph * 32 + q * 8;
      src = W1 + (size_t)col * 513 + k;
      scale = 64.f;
    } else {                                        // W2 frag: m=dz-col, k=h-col
      int col = w * 64 + nt * 16 + m16;
      int k = ch * 512 + (ph - 16) * 32 + q * 8;
      src = W2 + (size_t)col * 1025 + k;
      scale = 1.f;
    }
    f16x8 hv;
    #pragma unroll
    for (int e = 0; e < 8; ++e) hv[e] = (_Float16)(src[e] * scale);
    *(f16x8*)(wp + (size_t)idx * 8) = hv;
  } else if (blk < 516) {                           // biases
    int j = (blk - 512) * 256 + tid;                // [0, 1024)
    float t0 = t[0];
    bias1[j] = b1[j] + t0 * W1[(size_t)j * 513 + 512];
    if (j < 512) bias2[j] = b2[j] + t0 * W2[(size_t)j * 1025 + 1024];
  } else {                                          // c[j] = sum_k W2[k,j]*W1[j,k]
    int wave = tid >> 6, lane = tid & 63;
    int j = (blk - 516) * 4 + wave;                 // [0, 1024)
    float s = 0.f;
    #pragma unroll
    for (int kk = 0; kk < 8; ++kk) {
      int k = lane + kk * 64;
      s += W2[(size_t)k * 1025 + j] * W1[(size_t)j * 513 + k];
    }
    #pragma unroll
    for (int off = 32; off > 0; off >>= 1) s += __shfl_xor(s, off);
    if (lane == 0) cvec[j] = s;
  }
}

// ---------------- fused: 64-row block, 8 waves, half-slice pipelined core ----------------
// Block = 64 z-rows, 512 threads (8 waves, 2/SIMD), grid 256 (1 block/CU).
// Wave w owns cols [w*64,+64); acc = 128 AGPR. Weights: double-buffered reg stream.
// Half-slice zf pipeline: the NEXT half's 2 ds_reads issue before the CURRENT
// half's 8 MFMAs (register-neutral ping-pong). NO setprio: waves are lockstep
// between barriers (m190: setprio hurts barrier-synced GEMM; only pays with
// wave role diversity).
// Tail: zv-once-per-row + QUARTER-wave parallel entries (4 at once, shfl merges).

__global__ __launch_bounds__(512) void fused_kernel(
    const float* __restrict__ z, const _Float16* __restrict__ wp,
    const float* __restrict__ W1f,
    const float* __restrict__ bias1, const float* __restrict__ bias2,
    const float* __restrict__ cvec,
    float* __restrict__ out, float* __restrict__ dlogp) {
  __shared__ __align__(16) _Float16 Az[64 * 512];   // 64 KB swizzled z (f16 x16)
  __shared__ __align__(16) _Float16 Hb[64 * 512];   // 64 KB swizzled h chunk
  __shared__ __align__(16) float bias1L[1024];      // 4 KB
  __shared__ __align__(16) float cvecL[1024];       // 4 KB
  __shared__ uint32_t rbuck[64][RCAP];              // 4 KB row-bucketed borderline
  __shared__ uint32_t rbcnt[64];                    // 256 B
  __shared__ uint32_t ovf[OCAP];                    // 128 B
  __shared__ float redbuf[8][64];                   // 2 KB
  __shared__ float fixv[64];                        // wave-owned corrections
  __shared__ float fixo[64];                        // overflow corrections
  __shared__ uint32_t ovfcnt;                       // ~143 KB total

  const int tid  = threadIdx.x;
  const int lane = tid & 63, w = tid >> 6;          // wave 0..7
  const int q    = lane >> 4, m16 = lane & 15;
  const int sw   = m16 & 7;
  const int bm   = blockIdx.x;                      // 256 blocks x 64 rows

  if (tid < 64) { rbcnt[tid] = 0; fixo[tid] = 0.f; }
  if (tid == 0) ovfcnt = 0;

  // ---- stage z (f32 -> f16 x16) into swizzled Az: 64x512 ----
  {
    const float* zp = z + (size_t)bm * 64 * 512;
    #pragma unroll
    for (int i = 0; i < 16; ++i) {
      int slot = i * 512 + tid;
      int row = slot >> 7, u8 = slot & 127;
      f32x4 v = *(const f32x4*)(zp + (size_t)row * 512 + u8 * 4);
      f16x4 hv;
      #pragma unroll
      for (int r = 0; r < 4; ++r) hv[r] = (_Float16)(v[r] * 16.f);
      int gz = (u8 >> 1) ^ (row & 7);
      *(f16x4*)((char*)Az + row * 1024 + gz * 16 + (u8 & 1) * 8) = hv;
    }
  }
  for (int i = tid; i < 1024; i += 512) {
    bias1L[i] = bias1[i];
    cvecL[i]  = cvec[i];
  }
  __syncthreads();

  f32x4 acc1[4][4] = {};                            // GEMM1: [mt(row16)][nt(col16)]
  f32x4 acc2[4][4] = {};                            // GEMM2 accumulates across chunks
  float tr[4] = {0.f, 0.f, 0.f, 0.f};

  const char* azb   = (const char*)Az + m16 * 1024;
  const char* hbb   = (const char*)Hb + m16 * 1024;
  const char* wbase = (const char*)wp + w * 4096 + lane * 16;

  f16x8 cwA[4], cwB[4];
  f16x8 zc0, zc1, zn0, zn1;                         // half-slice zf ping-pong
  {
    const char* wb = wbase;                         // slice 0
    cwA[0] = *(const f16x8*)(wb);
    cwA[1] = *(const f16x8*)(wb + 1024);
    cwA[2] = *(const f16x8*)(wb + 2048);
    cwA[3] = *(const f16x8*)(wb + 3072);
  }

  for (int ch = 0; ch < 2; ++ch) {
    // ---- GEMM1: 16 k32-slices; half-slice zf pipeline ----
    {
      const int zg = (q ^ sw) << 4;                 // (s=0, half0)
      zc0 = *(const f16x8*)(azb + zg);
      zc1 = *(const f16x8*)(azb + 16384 + zg);
    }
    for (int s2 = 0; s2 < 8; ++s2) {
      const int s = s2 * 2;
      const int g = ch * 32 + s;
      {
        const char* wb = wbase + (size_t)(g + 1) * 32768;
        cwB[0] = *(const f16x8*)(wb);
        cwB[1] = *(const f16x8*)(wb + 1024);
        cwB[2] = *(const f16x8*)(wb + 2048);
        cwB[3] = *(const f16x8*)(wb + 3072);
      }
      {   // prefetch (s, half1); compute (s, half0) with cwA
        const int zg = ((s * 4 + q) ^ sw) << 4;
        zn0 = *(const f16x8*)(azb + 32768 + zg);
        zn1 = *(const f16x8*)(azb + 49152 + zg);
        acc1[0][0] = MFMA(cwA[0], zc0, acc1[0][0]);
        acc1[0][1] = MFMA(cwA[1], zc0, acc1[0][1]);
        acc1[0][2] = MFMA(cwA[2], zc0, acc1[0][2]);
        acc1[0][3] = MFMA(cwA[3], zc0, acc1[0][3]);
        acc1[1][0] = MFMA(cwA[0], zc1, acc1[1][0]);
        acc1[1][1] = MFMA(cwA[1], zc1, acc1[1][1]);
        acc1[1][2] = MFMA(cwA[2], zc1, acc1[1][2]);
        acc1[1][3] = MFMA(cwA[3], zc1, acc1[1][3]);
      }
      {   // prefetch (s+1, half0); compute (s, half1) with cwA
        const int zg = (((s + 1) * 4 + q) ^ sw) << 4;
        zc0 = *(const f16x8*)(azb + zg);
        zc1 = *(const f16x8*)(azb + 16384 + zg);
        acc1[2][0] = MFMA(cwA[0], zn0, acc1[2][0]);
        acc1[2][1] = MFMA(cwA[1], zn0, acc1[2][1]);
        acc1[2][2] = MFMA(cwA[2], zn0, acc1[2][2]);
        acc1[2][3] = MFMA(cwA[3], zn0, acc1[2][3]);
        acc1[3][0] = MFMA(cwA[0], zn1, acc1[3][0]);
        acc1[3][1] = MFMA(cwA[1], zn1, acc1[3][1]);
        acc1[3][2] = MFMA(cwA[2], zn1, acc1[3][2]);
        acc1[3][3] = MFMA(cwA[3], zn1, acc1[3][3]);
      }
      {
        const int gn = (g + 2 > 63) ? 63 : (g + 2);
        const char* wb = wbase + (size_t)gn * 32768;
        cwA[0] = *(const f16x8*)(wb);
        cwA[1] = *(const f16x8*)(wb + 1024);
        cwA[2] = *(const f16x8*)(wb + 2048);
        cwA[3] = *(const f16x8*)(wb + 3072);
      }
      {   // prefetch (s+1, half1); compute (s+1, half0) with cwB
        const int zg = (((s + 1) * 4 + q) ^ sw) << 4;
        zn0 = *(const f16x8*)(azb + 32768 + zg);
        zn1 = *(const f16x8*)(azb + 49152 + zg);
        acc1[0][0] = MFMA(cwB[0], zc0, acc1[0][0]);
        acc1[0][1] = MFMA(cwB[1], zc0, acc1[0][1]);
        acc1[0][2] = MFMA(cwB[2], zc0, acc1[0][2]);
        acc1[0][3] = MFMA(cwB[3], zc0, acc1[0][3]);
        acc1[1][0] = MFMA(cwB[0], zc1, acc1[1][0]);
        acc1[1][1] = MFMA(cwB[1], zc1, acc1[1][1]);
        acc1[1][2] = MFMA(cwB[2], zc1, acc1[1][2]);
        acc1[1][3] = MFMA(cwB[3], zc1, acc1[1][3]);
      }
      {   // prefetch (s+2, half0) [clamped]; compute (s+1, half1) with cwB
        const int sn = (s + 2 > 15) ? 15 : (s + 2);
        const int zg = ((sn * 4 + q) ^ sw) << 4;
        zc0 = *(const f16x8*)(azb + zg);
        zc1 = *(const f16x8*)(azb + 16384 + zg);
        acc1[2][0] = MFMA(cwB[0], zn0, acc1[2][0]);
        acc1[2][1] = MFMA(cwB[1], zn0, acc1[2][1]);
        acc1[2][2] = MFMA(cwB[2], zn0, acc1[2][2]);
        acc1[2][3] = MFMA(cwB[3], zn0, acc1[2][3]);
        acc1[3][0] = MFMA(cwB[0], zn1, acc1[3][0]);
        acc1[3][1] = MFMA(cwB[1], zn1, acc1[3][1]);
        acc1[3][2] = MFMA(cwB[2], zn1, acc1[3][2]);
        acc1[3][3] = MFMA(cwB[3], zn1, acc1[3][3]);
      }
    }

    __syncthreads();   // A: all waves finished reading Hb in previous GEMM2

    // ---- chunk epilogue: bias+relu, trace, row-bucketed borderline, h -> Hb ----
    #pragma unroll
    for (int nt = 0; nt < 4; ++nt) {
      int colc = w * 64 + nt * 16 + q * 4;          // chunk-local col
      int col = ch * 512 + colc;
      f32x4 b4 = *(const f32x4*)&bias1L[col];
      f32x4 c4 = *(const f32x4*)&cvecL[col];
      #pragma unroll
      for (int mt = 0; mt < 4; ++mt) {
        int row = mt * 16 + m16;
        f16x4 hv;
        #pragma unroll
        for (int r = 0; r < 4; ++r) {
          float hp = acc1[mt][nt][r] * (1.f / 1024.f) + b4[r];
          hv[r] = (_Float16)(hp > 0.f ? hp : 0.f);
          if (hp > 0.f) tr[mt] += c4[r];
          if (__builtin_fabsf(hp) < DELTA) {
            uint32_t e = (uint32_t)(col + r) | (hp > 0.f ? 0x80000000u : 0u);
            uint32_t bi = atomicAdd(&rbcnt[row], 1u);   // LDS atomic: cheap
            if (bi < RCAP) rbuck[row][bi] = e;
            else {
              uint32_t oi = atomicAdd(&ovfcnt, 1u);
              if (oi < OCAP) ovf[oi] = ((uint32_t)row << 10) | e;
            }
          }
        }
        int gg = (colc >> 3) ^ (row & 7);
        *(f16x4*)((char*)Hb + row * 1024 + gg * 16 + (q & 1) * 8) = hv;
        acc1[mt][nt] = (f32x4){0.f, 0.f, 0.f, 0.f};
      }
    }

    __syncthreads();   // B: Hb(ch) visible to all waves

    // ---- GEMM2: 16 k32-slices, dz += h_chunk @ W2[:, ch*512..]^T ----
    {
      const int zg = (q ^ sw) << 4;                 // (t=0, half0)
      zc0 = *(const f16x8*)(hbb + zg);
      zc1 = *(const f16x8*)(hbb + 16384 + zg);
    }
    for (int t2 = 0; t2 < 8; ++t2) {
      const int t = t2 * 2;
      const int g = ch * 32 + 16 + t;
      {
        const char* wb = wbase + (size_t)(g + 1) * 32768;
        cwB[0] = *(const f16x8*)(wb);
        cwB[1] = *(const f16x8*)(wb + 1024);
        cwB[2] = *(const f16x8*)(wb + 2048);
        cwB[3] = *(const f16x8*)(wb + 3072);
      }
      {   // prefetch (t, half1); compute (t, half0) with cwA
        const int zg = ((t * 4 + q) ^ sw) << 4;
        zn0 = *(const f16x8*)(hbb + 32768 + zg);
        zn1 = *(const f16x8*)(hbb + 49152 + zg);
        acc2[0][0] = MFMA(cwA[0], zc0, acc2[0][0]);
        acc2[0][1] = MFMA(cwA[1], zc0, acc2[0][1]);
        acc2[0][2] = MFMA(cwA[2], zc0, acc2[0][2]);
        acc2[0][3] = MFMA(cwA[3], zc0, acc2[0][3]);
        acc2[1][0] = MFMA(cwA[0], zc1, acc2[1][0]);
        acc2[1][1] = MFMA(cwA[1], zc1, acc2[1][1]);
        acc2[1][2] = MFMA(cwA[2], zc1, acc2[1][2]);
        acc2[1][3] = MFMA(cwA[3], zc1, acc2[1][3]);
      }
      {   // prefetch (t+1, half0); compute (t, half1) with cwA
        const int zg = (((t + 1) * 4 + q) ^ sw) << 4;
        zc0 = *(const f16x8*)(hbb + zg);
        zc1 = *(const f16x8*)(hbb + 16384 + zg);
        acc2[2][0] = MFMA(cwA[0], zn0, acc2[2][0]);
        acc2[2][1] = MFMA(cwA[1], zn0, acc2[2][1]);
        acc2[2][2] = MFMA(cwA[2], zn0, acc2[2][2]);
        acc2[2][3] = MFMA(cwA[3], zn0, acc2[2][3]);
        acc2[3][0] = MFMA(cwA[0], zn1, acc2[3][0]);
        acc2[3][1] = MFMA(cwA[1], zn1, acc2[3][1]);
        acc2[3][2] = MFMA(cwA[2], zn1, acc2[3][2]);
        acc2[3][3] = MFMA(cwA[3], zn1, acc2[3][3]);
      }
      {
        const int gn = (g + 2 > 63) ? 63 : (g + 2);
        const char* wb = wbase + (size_t)gn * 32768;
        cwA[0] = *(const f16x8*)(wb);
        cwA[1] = *(const f16x8*)(wb + 1024);
        cwA[2] = *(const f16x8*)(wb + 2048);
        cwA[3] = *(const f16x8*)(wb + 3072);
      }
      {   // prefetch (t+1, half1); compute (t+1, half0) with cwB
        const int zg = (((t + 1) * 4 + q) ^ sw) << 4;
        zn0 = *(const f16x8*)(hbb + 32768 + zg);
        zn1 = *(const f16x8*)(hbb + 49152 + zg);
        acc2[0][0] = MFMA(cwB[0], zc0, acc2[0][0]);
        acc2[0][1] = MFMA(cwB[1], zc0, acc2[0][1]);
        acc2[0][2] = MFMA(cwB[2], zc0, acc2[0][2]);
        acc2[0][3] = MFMA(cwB[3], zc0, acc2[0][3]);
        acc2[1][0] = MFMA(cwB[0], zc1, acc2[1][0]);
        acc2[1][1] = MFMA(cwB[1], zc1, acc2[1][1]);
        acc2[1][2] = MFMA(cwB[2], zc1, acc2[1][2]);
        acc2[1][3] = MFMA(cwB[3], zc1, acc2[1][3]);
      }
      {   // prefetch (t+2, half0) [clamped]; compute (t+1, half1) with cwB
        const int tn = (t + 2 > 15) ? 15 : (t + 2);
        const int zg = ((tn * 4 + q) ^ sw) << 4;
        zc0 = *(const f16x8*)(hbb + zg);
        zc1 = *(const f16x8*)(hbb + 16384 + zg);
        acc2[2][0] = MFMA(cwB[0], zn0, acc2[2][0]);
        acc2[2][1] = MFMA(cwB[1], zn0, acc2[2][1]);
        acc2[2][2] = MFMA(cwB[2], zn0, acc2[2][2]);
        acc2[2][3] = MFMA(cwB[3], zn0, acc2[2][3]);
        acc2[3][0] = MFMA(cwB[0], zn1, acc2[3][0]);
        acc2[3][1] = MFMA(cwB[1], zn1, acc2[3][1]);
        acc2[3][2] = MFMA(cwB[2], zn1, acc2[3][2]);
        acc2[3][3] = MFMA(cwB[3], zn1, acc2[3][3]);
      }
    }
  }

  // ---- dz store: +bias2, f32x4 (4 consecutive cols per thread) ----
  #pragma unroll
  for (int mt = 0; mt < 4; ++mt) {
    int row = bm * 64 + mt * 16 + m16;
    #pragma unroll
    for (int nt = 0; nt < 4; ++nt) {
      int col = w * 64 + nt * 16 + q * 4;
      f32x4 b2v = *(const f32x4*)(bias2 + col);
      *(f32x4*)(out + (size_t)row * 512 + col) = acc2[mt][nt] + b2v;
    }
  }

  // ---- trace: block-local partials to LDS ----
  #pragma unroll
  for (int mt = 0; mt < 4; ++mt) {
    tr[mt] += __shfl_xor(tr[mt], 16);
    tr[mt] += __shfl_xor(tr[mt], 32);
  }
  if (q == 0) {
    #pragma unroll
    for (int mt = 0; mt < 4; ++mt) redbuf[w][mt * 16 + m16] = tr[mt];
  }
  __syncthreads();   // redbuf + rbuck/rbcnt/ovf final

  // ---- in-block fixup: wave w owns rows [w*8,+8); zv once/row; QUARTER-parallel ----
  {
    const int qlane = lane & 15;                    // lane within quarter-wave
    const int qid   = lane >> 4;                    // 0..3
    #pragma unroll 1
    for (int r8 = 0; r8 < 8; ++r8) {
      int row = w * 8 + r8;
      uint32_t cnt = rbcnt[row];
      if (cnt > RCAP) cnt = RCAP;
      float corr = 0.f;
      if (cnt) {
        const float* zr = z + ((size_t)(bm * 64 + row)) * 512;
        float zv[32];
        #pragma unroll
        for (int it = 0; it < 32; ++it) zv[it] = zr[it * 16 + qlane];
        for (uint32_t e = 0; e < cnt; e += 4) {
          uint32_t idx = e + (uint32_t)qid;
          int act = idx < cnt;
          uint32_t en = rbuck[row][act ? idx : e];
          int col  = (int)(en & 1023u);
          int oldm = (int)(en >> 31);
          const float* wc = W1f + (size_t)col * 513;
          float s = 0.f;
          #pragma unroll
          for (int it = 0; it < 32; ++it) s += zv[it] * wc[it * 16 + qlane];
          #pragma unroll
          for (int off = 8; off > 0; off >>= 1) s += __shfl_xor(s, off);
          float hp = s + bias1L[col];
          int newm = hp > 0.f ? 1 : 0;
          float delta = (act && newm != oldm) ? (oldm ? cvecL[col] : -cvecL[col]) : 0.f;
          delta += __shfl_xor(delta, 16);           // merge 4 quarters
          delta += __shfl_xor(delta, 32);
          corr += delta;                            // valid in lane 0
        }
      }
      if (lane == 0) fixv[row] = corr;              // wave-owned: plain store
    }
  }
  // overflow entries (statistically never; correctness safety net)
  {
    uint32_t on = ovfcnt;
    if (on > OCAP) on = OCAP;
    for (uint32_t i = w; i < on; i += 8) {
      uint32_t e = ovf[i];
      int row  = (int)((e >> 10) & 63u);
      int col  = (int)(e & 1023u);
      int oldm = (int)(e >> 31);
      const float* zr = z + ((size_t)(bm * 64 + row)) * 512;
      const float* wc = W1f + (size_t)col * 513;
      float s = 0.f;
      #pragma unroll
      for (int it = 0; it < 8; ++it) {
        int k = it * 64 + lane;
        s += zr[k] * wc[k];
      }
      #pragma unroll
      for (int off = 32; off > 0; off >>= 1) s += __shfl_xor(s, off);
      if (lane == 0) {
        float hp = s + bias1L[col];
        int newm = hp > 0.f ? 1 : 0;
        if (newm != oldm) atomicAdd(&fixo[row], oldm ? cvecL[col] : -cvecL[col]);
      }
    }
  }
  __syncthreads();

  // ---- final dlogp: -(trace) + corrections, deterministic store ----
  if (tid < 64) {
    float s = 0.f;
    #pragma unroll
    for (int ww = 0; ww < 8; ++ww) s += redbuf[ww][tid];
    dlogp[bm * 64 + tid] = -s + fixv[tid] + fixo[tid];
  }
}

// ---------------- launcher ----------------
extern "C" void kernel_launch(void* const* d_in, const int* in_sizes, int n_in,
                              void* d_out, int out_size, void* d_ws, size_t ws_size,
                              hipStream_t stream) {
  const float* t  = (const float*)d_in[0];
  const float* z  = (const float*)d_in[1];
  // d_in[2] = logp_z, unused
  const float* W1 = (const float*)d_in[3];
  const float* b1 = (const float*)d_in[4];
  const float* W2 = (const float*)d_in[5];
  const float* b2 = (const float*)d_in[6];

  float* out   = (float*)d_out;
  float* dlogp = out + (size_t)B_ * D_;

  char* ws = (char*)d_ws;
  _Float16* wp    = (_Float16*)ws; ws += (size_t)64 * 32768;     // 2 MB permuted weights
  float*    bias1 = (float*)ws;    ws += 1024 * 4;
  float*    bias2 = (float*)ws;    ws += 512 * 4;
  float*    cvec  = (float*)ws;    ws += 1024 * 4;

  prep_w<<<772, 256, 0, stream>>>(t, W1, b1, W2, b2, wp, bias1, bias2, cvec);
  fused_kernel<<<256, 512, 0, stream>>>(z, wp, W1, bias1, bias2, cvec, out, dlogp);
}